// Round 1
// baseline (8763.195 us; speedup 1.0000x reference)
//
#include <hip/hip_runtime.h>

#define NN 500000

// ---------------- init: deg = 1 (self loop), t = 0 ----------------
__global__ void k_init(float* __restrict__ deg, float4* __restrict__ t, int n) {
    int i = blockIdx.x * blockDim.x + threadIdx.x;
    if (i < n) {
        deg[i] = 1.0f;
        t[i] = make_float4(0.f, 0.f, 0.f, 0.f);
    }
}

// ---------------- degree: deg[dst] += 1 per edge ----------------
__global__ void k_degree(const int* __restrict__ dst, float* __restrict__ deg, int ne) {
    int e = blockIdx.x * blockDim.x + threadIdx.x;
    if (e < ne) unsafeAtomicAdd(&deg[dst[e]], 1.0f);
}

// ---------------- dis = rsqrt(deg), in place ----------------
__global__ void k_dis(float* __restrict__ deg, int n) {
    int i = blockIdx.x * blockDim.x + threadIdx.x;
    if (i < n) deg[i] = rsqrtf(deg[i]);
}

// ---------------- g1 = dis * (x @ W1), wave-per-row ----------------
__global__ __launch_bounds__(256) void k_xw(const float* __restrict__ x,
                                            const float* __restrict__ W1,
                                            const float* __restrict__ dis,
                                            float4* __restrict__ g, int n) {
    __shared__ float4 sW[128];
    int tid = threadIdx.x;
    if (tid < 128) sW[tid] = ((const float4*)W1)[tid];
    __syncthreads();
    int wave = tid >> 6, lane = tid & 63;
    int row = blockIdx.x * 4 + wave;
    if (row >= n) return;
    float2 xv = ((const float2*)(x + (size_t)row * 128))[lane];
    float4 w0 = sW[2 * lane], w1 = sW[2 * lane + 1];
    float a0 = xv.x * w0.x + xv.y * w1.x;
    float a1 = xv.x * w0.y + xv.y * w1.y;
    float a2 = xv.x * w0.z + xv.y * w1.z;
    float a3 = xv.x * w0.w + xv.y * w1.w;
    for (int off = 32; off; off >>= 1) {
        a0 += __shfl_xor(a0, off);
        a1 += __shfl_xor(a1, off);
        a2 += __shfl_xor(a2, off);
        a3 += __shfl_xor(a3, off);
    }
    if (lane == 0) {
        float dv = dis[row];
        g[row] = make_float4(dv * a0, dv * a1, dv * a2, dv * a3);
    }
}

// ---------------- edge scatter, 4-wide: t[dst] += g[src] ----------------
__global__ void k_edge4(const int* __restrict__ src, const int* __restrict__ dst,
                        const float4* __restrict__ g, float* __restrict__ t, int ne) {
    int e = blockIdx.x * blockDim.x + threadIdx.x;
    if (e >= ne) return;
    int s = src[e], d = dst[e];
    float4 gv = g[s];
    float* tp = t + (size_t)d * 4;
    unsafeAtomicAdd(tp + 0, gv.x);
    unsafeAtomicAdd(tp + 1, gv.y);
    unsafeAtomicAdd(tp + 2, gv.z);
    unsafeAtomicAdd(tp + 3, gv.w);
}

// ---------------- edge scatter, 2-wide ----------------
__global__ void k_edge2(const int* __restrict__ src, const int* __restrict__ dst,
                        const float2* __restrict__ g3, float* __restrict__ t, int ne) {
    int e = blockIdx.x * blockDim.x + threadIdx.x;
    if (e >= ne) return;
    int s = src[e], d = dst[e];
    float2 gv = g3[s];
    unsafeAtomicAdd(t + 2 * (size_t)d + 0, gv.x);
    unsafeAtomicAdd(t + 2 * (size_t)d + 1, gv.y);
}

// ------- post layer (4 -> 4): h=tanh(dis*(t+g)+b); g = dis*(h@W); t=0 -------
__global__ void k_post44(const float* __restrict__ dis, float4* __restrict__ g,
                         float4* __restrict__ t, const float* __restrict__ b,
                         const float* __restrict__ W /*4x4 row-major*/, int n) {
    int i = blockIdx.x * blockDim.x + threadIdx.x;
    if (i >= n) return;
    float dv = dis[i];
    float4 tv = t[i], gv = g[i];
    float h0 = tanhf(dv * (tv.x + gv.x) + b[0]);
    float h1 = tanhf(dv * (tv.y + gv.y) + b[1]);
    float h2 = tanhf(dv * (tv.z + gv.z) + b[2]);
    float h3 = tanhf(dv * (tv.w + gv.w) + b[3]);
    float4 o;
    o.x = dv * (h0 * W[0] + h1 * W[4] + h2 * W[8]  + h3 * W[12]);
    o.y = dv * (h0 * W[1] + h1 * W[5] + h2 * W[9]  + h3 * W[13]);
    o.z = dv * (h0 * W[2] + h1 * W[6] + h2 * W[10] + h3 * W[14]);
    o.w = dv * (h0 * W[3] + h1 * W[7] + h2 * W[11] + h3 * W[15]);
    g[i] = o;
    t[i] = make_float4(0.f, 0.f, 0.f, 0.f);
}

// ------- post layer (4 -> 2): h=tanh(dis*(t+g)+b); g3 = dis*(h@W3); t=0 -------
__global__ void k_post42(const float* __restrict__ dis, const float4* __restrict__ g,
                         float4* __restrict__ t, const float* __restrict__ b,
                         const float* __restrict__ W /*4x2 row-major*/,
                         float2* __restrict__ g3, int n) {
    int i = blockIdx.x * blockDim.x + threadIdx.x;
    if (i >= n) return;
    float dv = dis[i];
    float4 tv = t[i], gv = g[i];
    float h0 = tanhf(dv * (tv.x + gv.x) + b[0]);
    float h1 = tanhf(dv * (tv.y + gv.y) + b[1]);
    float h2 = tanhf(dv * (tv.z + gv.z) + b[2]);
    float h3 = tanhf(dv * (tv.w + gv.w) + b[3]);
    float2 o;
    o.x = dv * (h0 * W[0] + h1 * W[2] + h2 * W[4] + h3 * W[6]);
    o.y = dv * (h0 * W[1] + h1 * W[3] + h2 * W[5] + h3 * W[7]);
    g3[i] = o;
    t[i] = make_float4(0.f, 0.f, 0.f, 0.f);
}

// ------- final: h3=tanh(dis*(t+g3)+b3); out = h3@Wc + bc; write both -------
__global__ void k_post_out(const float* __restrict__ dis, const float2* __restrict__ g3,
                           const float2* __restrict__ t2, const float* __restrict__ b3,
                           const float* __restrict__ Wc /*2x4*/, const float* __restrict__ bc,
                           float4* __restrict__ out, float2* __restrict__ hout, int n) {
    int i = blockIdx.x * blockDim.x + threadIdx.x;
    if (i >= n) return;
    float dv = dis[i];
    float2 tv = t2[i], gv = g3[i];
    float h0 = tanhf(dv * (tv.x + gv.x) + b3[0]);
    float h1 = tanhf(dv * (tv.y + gv.y) + b3[1]);
    float4 o;
    o.x = h0 * Wc[0] + h1 * Wc[4] + bc[0];
    o.y = h0 * Wc[1] + h1 * Wc[5] + bc[1];
    o.z = h0 * Wc[2] + h1 * Wc[6] + bc[2];
    o.w = h0 * Wc[3] + h1 * Wc[7] + bc[3];
    out[i] = o;
    hout[i] = make_float2(h0, h1);
}

extern "C" void kernel_launch(void* const* d_in, const int* in_sizes, int n_in,
                              void* d_out, int out_size, void* d_ws, size_t ws_size,
                              hipStream_t stream) {
    const float* x  = (const float*)d_in[0];
    const int*   ei = (const int*)d_in[1];
    const float* W1 = (const float*)d_in[2];
    const float* b1 = (const float*)d_in[3];
    const float* W2 = (const float*)d_in[4];
    const float* b2 = (const float*)d_in[5];
    const float* W3 = (const float*)d_in[6];
    const float* b3 = (const float*)d_in[7];
    const float* Wc = (const float*)d_in[8];
    const float* bc = (const float*)d_in[9];

    const int n  = NN;
    const int ne = in_sizes[1] / 2;
    const int* src  = ei;
    const int* dstp = ei + ne;

    // workspace layout (floats): dis[n] | g[4n] | t[4n] | g3[2n]  = 11n = 22 MB
    float* ws  = (float*)d_ws;
    float* dis = ws;
    float* g   = ws + (size_t)n;
    float* t   = ws + 5 * (size_t)n;
    float* g3  = ws + 9 * (size_t)n;

    const int nb = (n + 255) / 256;
    const int eb = (ne + 255) / 256;

    k_init<<<nb, 256, 0, stream>>>(dis, (float4*)t, n);
    k_degree<<<eb, 256, 0, stream>>>(dstp, dis, ne);
    k_dis<<<nb, 256, 0, stream>>>(dis, n);

    // layer 1
    k_xw<<<(n + 3) / 4, 256, 0, stream>>>(x, W1, dis, (float4*)g, n);
    k_edge4<<<eb, 256, 0, stream>>>(src, dstp, (const float4*)g, t, ne);
    k_post44<<<nb, 256, 0, stream>>>(dis, (float4*)g, (float4*)t, b1, W2, n);

    // layer 2
    k_edge4<<<eb, 256, 0, stream>>>(src, dstp, (const float4*)g, t, ne);
    k_post42<<<nb, 256, 0, stream>>>(dis, (const float4*)g, (float4*)t, b2, W3, (float2*)g3, n);

    // layer 3 (2-wide) + classifier
    k_edge2<<<eb, 256, 0, stream>>>(src, dstp, (const float2*)g3, t, ne);
    k_post_out<<<nb, 256, 0, stream>>>(dis, (const float2*)g3, (const float2*)t, b3, Wc, bc,
                                       (float4*)d_out, (float2*)((float*)d_out + 4 * (size_t)n), n);
}

// Round 2
// 2000.831 us; speedup vs baseline: 4.3798x; 4.3798x over previous
//
#include <hip/hip_runtime.h>

#define NN 500000

// ============================================================================
// CSR-build + pull-gather GCN.
//   cnt[dst]++  (histogram == degree-1)
//   off = exclusive_scan(cnt); cur = off
//   ssrc[atomicAdd(cur[dst])] = src          (the only per-edge atomic pass)
//   3 fused pull layers: t[i] = sum_{e in CSR[i]} g[ssrc[e]] ; epilogue inline
// g is pre-scaled by dis so edges need no norm reads:
//   g = dis * (h @ W);  h_next = tanh(dis*(t + g_self) + b)
// ============================================================================

// ---------------- histogram: cnt[dst]++ (4 edges/thread) ----------------
__global__ __launch_bounds__(256) void k_hist(const int* __restrict__ dst,
                                              int* __restrict__ cnt, int ne) {
    int e = (blockIdx.x * blockDim.x + threadIdx.x) * 4;
    if (e + 3 < ne) {
        int4 d = *(const int4*)(dst + e);
        atomicAdd(&cnt[d.x], 1);
        atomicAdd(&cnt[d.y], 1);
        atomicAdd(&cnt[d.z], 1);
        atomicAdd(&cnt[d.w], 1);
    } else {
        for (int k = e; k < ne; ++k) atomicAdd(&cnt[dst[k]], 1);
    }
}

// ---------------- scan stage 1: per-block scan of 1024 items ----------------
__global__ __launch_bounds__(256) void k_scan1(const int* __restrict__ cnt,
                                               int* __restrict__ off,
                                               int* __restrict__ blksum, int n) {
    __shared__ int sh[256];
    int t = threadIdx.x;
    int base = blockIdx.x * 1024 + t * 4;
    int v0 = 0, v1 = 0, v2 = 0, v3 = 0;
    if (base + 3 < n) {
        int4 v = *(const int4*)(cnt + base);
        v0 = v.x; v1 = v.y; v2 = v.z; v3 = v.w;
    } else if (base < n) {
        v0 = cnt[base];
        if (base + 1 < n) v1 = cnt[base + 1];
        if (base + 2 < n) v2 = cnt[base + 2];
    }
    int tot = v0 + v1 + v2 + v3;
    sh[t] = tot;
    __syncthreads();
    for (int o = 1; o < 256; o <<= 1) {
        int a = (t >= o) ? sh[t - o] : 0;
        __syncthreads();
        sh[t] += a;
        __syncthreads();
    }
    int excl = sh[t] - tot;
    int e0 = excl, e1 = e0 + v0, e2 = e1 + v1, e3 = e2 + v2;
    if (base + 3 < n) {
        *(int4*)(off + base) = make_int4(e0, e1, e2, e3);
    } else if (base < n) {
        off[base] = e0;
        if (base + 1 < n) off[base + 1] = e1;
        if (base + 2 < n) off[base + 2] = e2;
    }
    if (t == 255) blksum[blockIdx.x] = sh[255];
}

// ---------------- scan stage 2: exclusive scan of block sums ----------------
__global__ __launch_bounds__(512) void k_scan2(int* __restrict__ blksum, int nb) {
    __shared__ int sh[512];
    int t = threadIdx.x;
    int v = (t < nb) ? blksum[t] : 0;
    sh[t] = v;
    __syncthreads();
    for (int o = 1; o < 512; o <<= 1) {
        int a = (t >= o) ? sh[t - o] : 0;
        __syncthreads();
        sh[t] += a;
        __syncthreads();
    }
    if (t < nb) blksum[t] = sh[t] - v;
}

// ---------------- scan stage 3: add block offsets, init cursors ----------------
__global__ __launch_bounds__(256) void k_scan3(int* __restrict__ off,
                                               const int* __restrict__ blksum,
                                               int* __restrict__ cur, int n) {
    int base = (blockIdx.x * 256 + threadIdx.x) * 4;
    if (base + 3 < n) {
        int add = blksum[base >> 10];
        int4 v = *(const int4*)(off + base);
        v.x += add; v.y += add; v.z += add; v.w += add;
        *(int4*)(off + base) = v;
        *(int4*)(cur + base) = v;
    } else if (base < n) {
        int add = blksum[base >> 10];
        for (int k = base; k < n; ++k) { int v = off[k] + add; off[k] = v; cur[k] = v; }
    }
}

// ---------------- scatter edges into CSR slots ----------------
__global__ __launch_bounds__(256) void k_scatter(const int* __restrict__ src,
                                                 const int* __restrict__ dst,
                                                 int* __restrict__ cur,
                                                 int* __restrict__ ssrc, int ne) {
    int e = (blockIdx.x * blockDim.x + threadIdx.x) * 4;
    if (e + 3 < ne) {
        int4 s = *(const int4*)(src + e);
        int4 d = *(const int4*)(dst + e);
        ssrc[atomicAdd(&cur[d.x], 1)] = s.x;
        ssrc[atomicAdd(&cur[d.y], 1)] = s.y;
        ssrc[atomicAdd(&cur[d.z], 1)] = s.z;
        ssrc[atomicAdd(&cur[d.w], 1)] = s.w;
    } else {
        for (int k = e; k < ne; ++k) ssrc[atomicAdd(&cur[dst[k]], 1)] = src[k];
    }
}

// ---------------- g1 = rsqrt(cnt+1) * (x @ W1), wave-per-row ----------------
__global__ __launch_bounds__(256) void k_xw(const float* __restrict__ x,
                                            const float* __restrict__ W1,
                                            const int* __restrict__ cnt,
                                            float4* __restrict__ g, int n) {
    __shared__ float4 sW[128];
    int tid = threadIdx.x;
    if (tid < 128) sW[tid] = ((const float4*)W1)[tid];
    __syncthreads();
    int wave = tid >> 6, lane = tid & 63;
    int row = blockIdx.x * 4 + wave;
    if (row >= n) return;
    float2 xv = ((const float2*)(x + (size_t)row * 128))[lane];
    float4 w0 = sW[2 * lane], w1 = sW[2 * lane + 1];
    float a0 = xv.x * w0.x + xv.y * w1.x;
    float a1 = xv.x * w0.y + xv.y * w1.y;
    float a2 = xv.x * w0.z + xv.y * w1.z;
    float a3 = xv.x * w0.w + xv.y * w1.w;
    for (int off = 32; off; off >>= 1) {
        a0 += __shfl_xor(a0, off);
        a1 += __shfl_xor(a1, off);
        a2 += __shfl_xor(a2, off);
        a3 += __shfl_xor(a3, off);
    }
    if (lane == 0) {
        float dv = rsqrtf((float)cnt[row] + 1.0f);
        g[row] = make_float4(dv * a0, dv * a1, dv * a2, dv * a3);
    }
}

// ---------------- pull layer 1: g1(f4) -> g2(f4) via W2,b1 ----------------
__global__ __launch_bounds__(256) void k_pull1(const int* __restrict__ off,
                                               const int* __restrict__ cnt,
                                               const int* __restrict__ ssrc,
                                               const float4* __restrict__ gin,
                                               const float* __restrict__ b,
                                               const float* __restrict__ W /*4x4*/,
                                               float4* __restrict__ gout, int n) {
    int tid = threadIdx.x;
    int node = blockIdx.x * 16 + (tid >> 4);
    int sl = tid & 15;
    if (node >= n) return;
    int begin = off[node], c = cnt[node];
    float4 acc = make_float4(0.f, 0.f, 0.f, 0.f);
    for (int k = sl; k < c; k += 16) {
        float4 gv = gin[ssrc[begin + k]];
        acc.x += gv.x; acc.y += gv.y; acc.z += gv.z; acc.w += gv.w;
    }
    for (int o = 1; o < 16; o <<= 1) {
        acc.x += __shfl_xor(acc.x, o);
        acc.y += __shfl_xor(acc.y, o);
        acc.z += __shfl_xor(acc.z, o);
        acc.w += __shfl_xor(acc.w, o);
    }
    if (sl == 0) {
        float dv = rsqrtf((float)c + 1.0f);
        float4 gs = gin[node];
        float h0 = tanhf(dv * (acc.x + gs.x) + b[0]);
        float h1 = tanhf(dv * (acc.y + gs.y) + b[1]);
        float h2 = tanhf(dv * (acc.z + gs.z) + b[2]);
        float h3 = tanhf(dv * (acc.w + gs.w) + b[3]);
        float4 o;
        o.x = dv * (h0 * W[0] + h1 * W[4] + h2 * W[8]  + h3 * W[12]);
        o.y = dv * (h0 * W[1] + h1 * W[5] + h2 * W[9]  + h3 * W[13]);
        o.z = dv * (h0 * W[2] + h1 * W[6] + h2 * W[10] + h3 * W[14]);
        o.w = dv * (h0 * W[3] + h1 * W[7] + h2 * W[11] + h3 * W[15]);
        gout[node] = o;
    }
}

// ---------------- pull layer 2: g2(f4) -> g3(f2) via W3,b2 ----------------
__global__ __launch_bounds__(256) void k_pull2(const int* __restrict__ off,
                                               const int* __restrict__ cnt,
                                               const int* __restrict__ ssrc,
                                               const float4* __restrict__ gin,
                                               const float* __restrict__ b,
                                               const float* __restrict__ W /*4x2*/,
                                               float2* __restrict__ gout, int n) {
    int tid = threadIdx.x;
    int node = blockIdx.x * 16 + (tid >> 4);
    int sl = tid & 15;
    if (node >= n) return;
    int begin = off[node], c = cnt[node];
    float4 acc = make_float4(0.f, 0.f, 0.f, 0.f);
    for (int k = sl; k < c; k += 16) {
        float4 gv = gin[ssrc[begin + k]];
        acc.x += gv.x; acc.y += gv.y; acc.z += gv.z; acc.w += gv.w;
    }
    for (int o = 1; o < 16; o <<= 1) {
        acc.x += __shfl_xor(acc.x, o);
        acc.y += __shfl_xor(acc.y, o);
        acc.z += __shfl_xor(acc.z, o);
        acc.w += __shfl_xor(acc.w, o);
    }
    if (sl == 0) {
        float dv = rsqrtf((float)c + 1.0f);
        float4 gs = gin[node];
        float h0 = tanhf(dv * (acc.x + gs.x) + b[0]);
        float h1 = tanhf(dv * (acc.y + gs.y) + b[1]);
        float h2 = tanhf(dv * (acc.z + gs.z) + b[2]);
        float h3 = tanhf(dv * (acc.w + gs.w) + b[3]);
        float2 o;
        o.x = dv * (h0 * W[0] + h1 * W[2] + h2 * W[4] + h3 * W[6]);
        o.y = dv * (h0 * W[1] + h1 * W[3] + h2 * W[5] + h3 * W[7]);
        gout[node] = o;
    }
}

// ---------------- pull layer 3 + classifier ----------------
__global__ __launch_bounds__(256) void k_pull3(const int* __restrict__ off,
                                               const int* __restrict__ cnt,
                                               const int* __restrict__ ssrc,
                                               const float2* __restrict__ gin,
                                               const float* __restrict__ b3,
                                               const float* __restrict__ Wc /*2x4*/,
                                               const float* __restrict__ bc,
                                               float4* __restrict__ out,
                                               float2* __restrict__ hout, int n) {
    int tid = threadIdx.x;
    int node = blockIdx.x * 16 + (tid >> 4);
    int sl = tid & 15;
    if (node >= n) return;
    int begin = off[node], c = cnt[node];
    float ax = 0.f, ay = 0.f;
    for (int k = sl; k < c; k += 16) {
        float2 gv = gin[ssrc[begin + k]];
        ax += gv.x; ay += gv.y;
    }
    for (int o = 1; o < 16; o <<= 1) {
        ax += __shfl_xor(ax, o);
        ay += __shfl_xor(ay, o);
    }
    if (sl == 0) {
        float dv = rsqrtf((float)c + 1.0f);
        float2 gs = gin[node];
        float h0 = tanhf(dv * (ax + gs.x) + b3[0]);
        float h1 = tanhf(dv * (ay + gs.y) + b3[1]);
        float4 o;
        o.x = h0 * Wc[0] + h1 * Wc[4] + bc[0];
        o.y = h0 * Wc[1] + h1 * Wc[5] + bc[1];
        o.z = h0 * Wc[2] + h1 * Wc[6] + bc[2];
        o.w = h0 * Wc[3] + h1 * Wc[7] + bc[3];
        out[node] = o;
        hout[node] = make_float2(h0, h1);
    }
}

// ============================================================================
// Fallback push path (round-0 kernels) — used only if ws_size is too small.
// ============================================================================
__global__ void k_init(float* __restrict__ deg, float4* __restrict__ t, int n) {
    int i = blockIdx.x * blockDim.x + threadIdx.x;
    if (i < n) { deg[i] = 1.0f; t[i] = make_float4(0.f, 0.f, 0.f, 0.f); }
}
__global__ void k_degree(const int* __restrict__ dst, float* __restrict__ deg, int ne) {
    int e = blockIdx.x * blockDim.x + threadIdx.x;
    if (e < ne) unsafeAtomicAdd(&deg[dst[e]], 1.0f);
}
__global__ void k_dis(float* __restrict__ deg, int n) {
    int i = blockIdx.x * blockDim.x + threadIdx.x;
    if (i < n) deg[i] = rsqrtf(deg[i]);
}
__global__ __launch_bounds__(256) void k_xw_dis(const float* __restrict__ x,
                                                const float* __restrict__ W1,
                                                const float* __restrict__ dis,
                                                float4* __restrict__ g, int n) {
    __shared__ float4 sW[128];
    int tid = threadIdx.x;
    if (tid < 128) sW[tid] = ((const float4*)W1)[tid];
    __syncthreads();
    int wave = tid >> 6, lane = tid & 63;
    int row = blockIdx.x * 4 + wave;
    if (row >= n) return;
    float2 xv = ((const float2*)(x + (size_t)row * 128))[lane];
    float4 w0 = sW[2 * lane], w1 = sW[2 * lane + 1];
    float a0 = xv.x * w0.x + xv.y * w1.x;
    float a1 = xv.x * w0.y + xv.y * w1.y;
    float a2 = xv.x * w0.z + xv.y * w1.z;
    float a3 = xv.x * w0.w + xv.y * w1.w;
    for (int off = 32; off; off >>= 1) {
        a0 += __shfl_xor(a0, off); a1 += __shfl_xor(a1, off);
        a2 += __shfl_xor(a2, off); a3 += __shfl_xor(a3, off);
    }
    if (lane == 0) {
        float dv = dis[row];
        g[row] = make_float4(dv * a0, dv * a1, dv * a2, dv * a3);
    }
}
__global__ void k_edge4(const int* __restrict__ src, const int* __restrict__ dst,
                        const float4* __restrict__ g, float* __restrict__ t, int ne) {
    int e = blockIdx.x * blockDim.x + threadIdx.x;
    if (e >= ne) return;
    int s = src[e], d = dst[e];
    float4 gv = g[s];
    float* tp = t + (size_t)d * 4;
    unsafeAtomicAdd(tp + 0, gv.x); unsafeAtomicAdd(tp + 1, gv.y);
    unsafeAtomicAdd(tp + 2, gv.z); unsafeAtomicAdd(tp + 3, gv.w);
}
__global__ void k_edge2(const int* __restrict__ src, const int* __restrict__ dst,
                        const float2* __restrict__ g3, float* __restrict__ t, int ne) {
    int e = blockIdx.x * blockDim.x + threadIdx.x;
    if (e >= ne) return;
    int s = src[e], d = dst[e];
    float2 gv = g3[s];
    unsafeAtomicAdd(t + 2 * (size_t)d + 0, gv.x);
    unsafeAtomicAdd(t + 2 * (size_t)d + 1, gv.y);
}
__global__ void k_post44(const float* __restrict__ dis, float4* __restrict__ g,
                         float4* __restrict__ t, const float* __restrict__ b,
                         const float* __restrict__ W, int n) {
    int i = blockIdx.x * blockDim.x + threadIdx.x;
    if (i >= n) return;
    float dv = dis[i];
    float4 tv = t[i], gv = g[i];
    float h0 = tanhf(dv * (tv.x + gv.x) + b[0]);
    float h1 = tanhf(dv * (tv.y + gv.y) + b[1]);
    float h2 = tanhf(dv * (tv.z + gv.z) + b[2]);
    float h3 = tanhf(dv * (tv.w + gv.w) + b[3]);
    float4 o;
    o.x = dv * (h0 * W[0] + h1 * W[4] + h2 * W[8]  + h3 * W[12]);
    o.y = dv * (h0 * W[1] + h1 * W[5] + h2 * W[9]  + h3 * W[13]);
    o.z = dv * (h0 * W[2] + h1 * W[6] + h2 * W[10] + h3 * W[14]);
    o.w = dv * (h0 * W[3] + h1 * W[7] + h2 * W[11] + h3 * W[15]);
    g[i] = o;
    t[i] = make_float4(0.f, 0.f, 0.f, 0.f);
}
__global__ void k_post42(const float* __restrict__ dis, const float4* __restrict__ g,
                         float4* __restrict__ t, const float* __restrict__ b,
                         const float* __restrict__ W, float2* __restrict__ g3, int n) {
    int i = blockIdx.x * blockDim.x + threadIdx.x;
    if (i >= n) return;
    float dv = dis[i];
    float4 tv = t[i], gv = g[i];
    float h0 = tanhf(dv * (tv.x + gv.x) + b[0]);
    float h1 = tanhf(dv * (tv.y + gv.y) + b[1]);
    float h2 = tanhf(dv * (tv.z + gv.z) + b[2]);
    float h3 = tanhf(dv * (tv.w + gv.w) + b[3]);
    float2 o;
    o.x = dv * (h0 * W[0] + h1 * W[2] + h2 * W[4] + h3 * W[6]);
    o.y = dv * (h0 * W[1] + h1 * W[3] + h2 * W[5] + h3 * W[7]);
    g3[i] = o;
    t[i] = make_float4(0.f, 0.f, 0.f, 0.f);
}
__global__ void k_post_out(const float* __restrict__ dis, const float2* __restrict__ g3,
                           const float2* __restrict__ t2, const float* __restrict__ b3,
                           const float* __restrict__ Wc, const float* __restrict__ bc,
                           float4* __restrict__ out, float2* __restrict__ hout, int n) {
    int i = blockIdx.x * blockDim.x + threadIdx.x;
    if (i >= n) return;
    float dv = dis[i];
    float2 tv = t2[i], gv = g3[i];
    float h0 = tanhf(dv * (tv.x + gv.x) + b3[0]);
    float h1 = tanhf(dv * (tv.y + gv.y) + b3[1]);
    float4 o;
    o.x = h0 * Wc[0] + h1 * Wc[4] + bc[0];
    o.y = h0 * Wc[1] + h1 * Wc[5] + bc[1];
    o.z = h0 * Wc[2] + h1 * Wc[6] + bc[2];
    o.w = h0 * Wc[3] + h1 * Wc[7] + bc[3];
    out[i] = o;
    hout[i] = make_float2(h0, h1);
}

extern "C" void kernel_launch(void* const* d_in, const int* in_sizes, int n_in,
                              void* d_out, int out_size, void* d_ws, size_t ws_size,
                              hipStream_t stream) {
    const float* x  = (const float*)d_in[0];
    const int*   ei = (const int*)d_in[1];
    const float* W1 = (const float*)d_in[2];
    const float* b1 = (const float*)d_in[3];
    const float* W2 = (const float*)d_in[4];
    const float* b2 = (const float*)d_in[5];
    const float* W3 = (const float*)d_in[6];
    const float* b3 = (const float*)d_in[7];
    const float* Wc = (const float*)d_in[8];
    const float* bc = (const float*)d_in[9];

    const int n  = NN;
    const int ne = in_sizes[1] / 2;
    const int* src  = ei;
    const int* dstp = ei + ne;

    const size_t nB  = (size_t)n * 4;
    const size_t neB = (size_t)ne * 4;
    const int NB1 = (n + 1023) / 1024;              // scan blocks (489)
    const size_t need = 13 * nB + neB + 4096;       // ~90 MB

    float4* out4  = (float4*)d_out;
    float2* hout2 = (float2*)((float*)d_out + 4 * (size_t)n);

    const int nb16 = (n + 15) / 16;                 // pull grid
    const int eb4  = (ne / 4 + 255) / 256;          // 4-edges/thread grid

    if (ws_size >= need) {
        char* base = (char*)d_ws;
        int* cnt  = (int*)base;
        int* off  = (int*)(base + 1 * nB);
        int* cur  = (int*)(base + 2 * nB);
        int* ssrc = (int*)(base + 3 * nB);
        float* g1 = (float*)(base + 3 * nB + neB);
        float* g2 = g1 + 4 * (size_t)n;
        float* g3 = g2 + 4 * (size_t)n;
        int* blksum = (int*)(g3 + 2 * (size_t)n);

        hipMemsetAsync(cnt, 0, nB, stream);
        k_hist<<<eb4, 256, 0, stream>>>(dstp, cnt, ne);
        k_scan1<<<NB1, 256, 0, stream>>>(cnt, off, blksum, n);
        k_scan2<<<1, 512, 0, stream>>>(blksum, NB1);
        k_scan3<<<NB1, 256, 0, stream>>>(off, blksum, cur, n);
        k_scatter<<<eb4, 256, 0, stream>>>(src, dstp, cur, ssrc, ne);

        k_xw<<<(n + 3) / 4, 256, 0, stream>>>(x, W1, cnt, (float4*)g1, n);
        k_pull1<<<nb16, 256, 0, stream>>>(off, cnt, ssrc, (const float4*)g1, b1, W2,
                                          (float4*)g2, n);
        k_pull2<<<nb16, 256, 0, stream>>>(off, cnt, ssrc, (const float4*)g2, b2, W3,
                                          (float2*)g3, n);
        k_pull3<<<nb16, 256, 0, stream>>>(off, cnt, ssrc, (const float2*)g3, b3, Wc, bc,
                                          out4, hout2, n);
    } else {
        // fallback: round-0 push path (22 MB)
        float* ws  = (float*)d_ws;
        float* dis = ws;
        float* g   = ws + (size_t)n;
        float* t   = ws + 5 * (size_t)n;
        float* g3  = ws + 9 * (size_t)n;
        const int nb = (n + 255) / 256;
        const int eb = (ne + 255) / 256;
        k_init<<<nb, 256, 0, stream>>>(dis, (float4*)t, n);
        k_degree<<<eb, 256, 0, stream>>>(dstp, dis, ne);
        k_dis<<<nb, 256, 0, stream>>>(dis, n);
        k_xw_dis<<<(n + 3) / 4, 256, 0, stream>>>(x, W1, dis, (float4*)g, n);
        k_edge4<<<eb, 256, 0, stream>>>(src, dstp, (const float4*)g, t, ne);
        k_post44<<<nb, 256, 0, stream>>>(dis, (float4*)g, (float4*)t, b1, W2, n);
        k_edge4<<<eb, 256, 0, stream>>>(src, dstp, (const float4*)g, t, ne);
        k_post42<<<nb, 256, 0, stream>>>(dis, (const float4*)g, (float4*)t, b2, W3,
                                         (float2*)g3, n);
        k_edge2<<<eb, 256, 0, stream>>>(src, dstp, (const float2*)g3, t, ne);
        k_post_out<<<nb, 256, 0, stream>>>(dis, (const float2*)g3, (const float2*)t, b3,
                                           Wc, bc, out4, hout2, n);
    }
}

// Round 3
// 1380.889 us; speedup vs baseline: 6.3461x; 1.4489x over previous
//
#include <hip/hip_runtime.h>

#define NN 500000
#define SH 9
#define NPB 512                          // nodes per bucket (1 << SH)
#define NBUCK ((NN + NPB - 1) / NPB)     // 977
#define PT_TILE 32768                    // edges per partition block

// ============================================================================
// Bucketed GCN:
//  1) k_bhist : per-bucket edge counts (LDS hist, one global atomic/bucket/blk)
//  2) k_bscan : exclusive scan of 977 bucket counts -> bbase, cur
//  3) k_part  : partition edges into buckets; packed = (src<<9)|(dst&511).
//               Per-block LDS hist -> one global reserve atomic per bucket ->
//               chunked writes (~134B contiguous per bucket per block).
//  4) k_deg   : per-bucket LDS node counts -> dis = rsqrt(deg+1), coalesced.
//  5) k_xw    : g1 = dis * (x @ W1)   (wave per row, shuffle reduce)
//  6) k_agg*  : per-bucket LDS float accumulation + fused epilogue:
//               h = tanh(dis*(acc + g_self) + b);  g_next = dis*(h @ W)
// ============================================================================

__global__ __launch_bounds__(256) void k_bhist(const int* __restrict__ dst,
                                               int* __restrict__ bcount, int ne) {
    __shared__ int lh[NBUCK];
    for (int i = threadIdx.x; i < NBUCK; i += 256) lh[i] = 0;
    __syncthreads();
    int ne4 = ne >> 2;
    for (int i = blockIdx.x * 256 + threadIdx.x; i < ne4; i += gridDim.x * 256) {
        int4 d = ((const int4*)dst)[i];
        atomicAdd(&lh[d.x >> SH], 1);
        atomicAdd(&lh[d.y >> SH], 1);
        atomicAdd(&lh[d.z >> SH], 1);
        atomicAdd(&lh[d.w >> SH], 1);
    }
    if (blockIdx.x == 0) {  // tail if ne % 4 != 0
        for (int k = (ne & ~3) + threadIdx.x; k < ne; k += 256)
            atomicAdd(&lh[dst[k] >> SH], 1);
    }
    __syncthreads();
    for (int i = threadIdx.x; i < NBUCK; i += 256)
        if (lh[i]) atomicAdd(&bcount[i], lh[i]);
}

__global__ __launch_bounds__(1024) void k_bscan(const int* __restrict__ bcount,
                                                int* __restrict__ bbase,
                                                int* __restrict__ cur) {
    __shared__ int sh[1024];
    int t = threadIdx.x;
    int v = (t < NBUCK) ? bcount[t] : 0;
    sh[t] = v;
    __syncthreads();
    for (int o = 1; o < 1024; o <<= 1) {
        int a = (t >= o) ? sh[t - o] : 0;
        __syncthreads();
        sh[t] += a;
        __syncthreads();
    }
    if (t < NBUCK) {
        int excl = sh[t] - v;
        bbase[t] = excl;
        cur[t] = excl;
        if (t == NBUCK - 1) bbase[NBUCK] = sh[t];
    }
}

__global__ __launch_bounds__(256) void k_part(const int* __restrict__ src,
                                              const int* __restrict__ dst,
                                              int* __restrict__ cur,
                                              int* __restrict__ packed, int ne) {
    __shared__ int lhist[NBUCK];
    __shared__ int lcur[NBUCK];
    int tid = threadIdx.x;
    for (int i = tid; i < NBUCK; i += 256) lhist[i] = 0;
    __syncthreads();
    int t0 = blockIdx.x * PT_TILE;
    int t1 = t0 + PT_TILE; if (t1 > ne) t1 = ne;
    // phase A: local bucket histogram
    for (int e = t0 + tid * 4; e < t1; e += 1024) {
        if (e + 3 < t1) {
            int4 d = *(const int4*)(dst + e);
            atomicAdd(&lhist[d.x >> SH], 1);
            atomicAdd(&lhist[d.y >> SH], 1);
            atomicAdd(&lhist[d.z >> SH], 1);
            atomicAdd(&lhist[d.w >> SH], 1);
        } else {
            for (int k = e; k < t1; ++k) atomicAdd(&lhist[dst[k] >> SH], 1);
        }
    }
    __syncthreads();
    // phase B: reserve global space, one atomic per non-empty bucket
    for (int i = tid; i < NBUCK; i += 256) {
        int c = lhist[i];
        lcur[i] = c ? atomicAdd(&cur[i], c) : 0;
    }
    __syncthreads();
    // phase C: write packed edges to reserved chunks
    for (int e = t0 + tid * 4; e < t1; e += 1024) {
        if (e + 3 < t1) {
            int4 d = *(const int4*)(dst + e);
            int4 s = *(const int4*)(src + e);
            int b, p;
            b = d.x >> SH; p = atomicAdd(&lcur[b], 1); packed[p] = (s.x << SH) | (d.x & (NPB - 1));
            b = d.y >> SH; p = atomicAdd(&lcur[b], 1); packed[p] = (s.y << SH) | (d.y & (NPB - 1));
            b = d.z >> SH; p = atomicAdd(&lcur[b], 1); packed[p] = (s.z << SH) | (d.z & (NPB - 1));
            b = d.w >> SH; p = atomicAdd(&lcur[b], 1); packed[p] = (s.w << SH) | (d.w & (NPB - 1));
        } else {
            for (int k = e; k < t1; ++k) {
                int dd = dst[k], ss = src[k];
                int b = dd >> SH;
                int p = atomicAdd(&lcur[b], 1);
                packed[p] = (ss << SH) | (dd & (NPB - 1));
            }
        }
    }
}

__global__ __launch_bounds__(256) void k_deg(const int* __restrict__ bbase,
                                             const int* __restrict__ packed,
                                             float* __restrict__ dis) {
    __shared__ int cnt[NPB];
    int tid = threadIdx.x, b = blockIdx.x;
    cnt[tid] = 0; cnt[tid + 256] = 0;
    __syncthreads();
    int e0 = bbase[b], e1 = bbase[b + 1];
    for (int e = e0 + tid; e < e1; e += 256)
        atomicAdd(&cnt[packed[e] & (NPB - 1)], 1);
    __syncthreads();
    int i0 = b << SH;
    for (int k = tid; k < NPB; k += 256) {
        int i = i0 + k;
        if (i < NN) dis[i] = rsqrtf((float)cnt[k] + 1.0f);
    }
}

// g1 = dis * (x @ W1), wave per row
__global__ __launch_bounds__(256) void k_xw(const float* __restrict__ x,
                                            const float* __restrict__ W1,
                                            const float* __restrict__ dis,
                                            float4* __restrict__ g, int n) {
    __shared__ float4 sW[128];
    int tid = threadIdx.x;
    if (tid < 128) sW[tid] = ((const float4*)W1)[tid];
    __syncthreads();
    int wave = tid >> 6, lane = tid & 63;
    int row = blockIdx.x * 4 + wave;
    if (row >= n) return;
    float2 xv = ((const float2*)(x + (size_t)row * 128))[lane];
    float4 w0 = sW[2 * lane], w1 = sW[2 * lane + 1];
    float a0 = xv.x * w0.x + xv.y * w1.x;
    float a1 = xv.x * w0.y + xv.y * w1.y;
    float a2 = xv.x * w0.z + xv.y * w1.z;
    float a3 = xv.x * w0.w + xv.y * w1.w;
    for (int off = 32; off; off >>= 1) {
        a0 += __shfl_xor(a0, off);
        a1 += __shfl_xor(a1, off);
        a2 += __shfl_xor(a2, off);
        a3 += __shfl_xor(a3, off);
    }
    if (lane == 0) {
        float dv = dis[row];
        g[row] = make_float4(dv * a0, dv * a1, dv * a2, dv * a3);
    }
}

// layer: gin f4 -> gout f4 via W (4x4 row-major), bias
__global__ __launch_bounds__(256) void k_agg44(const int* __restrict__ bbase,
                                               const int* __restrict__ packed,
                                               const float4* __restrict__ gin,
                                               const float* __restrict__ dis,
                                               const float* __restrict__ bias,
                                               const float* __restrict__ W,
                                               float4* __restrict__ gout) {
    __shared__ float acc[NPB * 4];
    int tid = threadIdx.x, b = blockIdx.x;
    for (int k = tid; k < NPB * 4; k += 256) acc[k] = 0.f;
    __syncthreads();
    int e0 = bbase[b], e1 = bbase[b + 1];
    for (int e = e0 + tid; e < e1; e += 256) {
        int p = packed[e];
        float4 gv = gin[p >> SH];
        float* a = &acc[(p & (NPB - 1)) * 4];
        unsafeAtomicAdd(a + 0, gv.x);
        unsafeAtomicAdd(a + 1, gv.y);
        unsafeAtomicAdd(a + 2, gv.z);
        unsafeAtomicAdd(a + 3, gv.w);
    }
    __syncthreads();
    int i0 = b << SH;
    for (int k = tid; k < NPB; k += 256) {
        int i = i0 + k;
        if (i >= NN) continue;
        float dv = dis[i];
        float4 gs = gin[i];
        float h0 = tanhf(dv * (acc[k * 4 + 0] + gs.x) + bias[0]);
        float h1 = tanhf(dv * (acc[k * 4 + 1] + gs.y) + bias[1]);
        float h2 = tanhf(dv * (acc[k * 4 + 2] + gs.z) + bias[2]);
        float h3 = tanhf(dv * (acc[k * 4 + 3] + gs.w) + bias[3]);
        float4 o;
        o.x = dv * (h0 * W[0] + h1 * W[4] + h2 * W[8]  + h3 * W[12]);
        o.y = dv * (h0 * W[1] + h1 * W[5] + h2 * W[9]  + h3 * W[13]);
        o.z = dv * (h0 * W[2] + h1 * W[6] + h2 * W[10] + h3 * W[14]);
        o.w = dv * (h0 * W[3] + h1 * W[7] + h2 * W[11] + h3 * W[15]);
        gout[i] = o;
    }
}

// layer: gin f4 -> gout f2 via W (4x2 row-major), bias
__global__ __launch_bounds__(256) void k_agg42(const int* __restrict__ bbase,
                                               const int* __restrict__ packed,
                                               const float4* __restrict__ gin,
                                               const float* __restrict__ dis,
                                               const float* __restrict__ bias,
                                               const float* __restrict__ W,
                                               float2* __restrict__ gout) {
    __shared__ float acc[NPB * 4];
    int tid = threadIdx.x, b = blockIdx.x;
    for (int k = tid; k < NPB * 4; k += 256) acc[k] = 0.f;
    __syncthreads();
    int e0 = bbase[b], e1 = bbase[b + 1];
    for (int e = e0 + tid; e < e1; e += 256) {
        int p = packed[e];
        float4 gv = gin[p >> SH];
        float* a = &acc[(p & (NPB - 1)) * 4];
        unsafeAtomicAdd(a + 0, gv.x);
        unsafeAtomicAdd(a + 1, gv.y);
        unsafeAtomicAdd(a + 2, gv.z);
        unsafeAtomicAdd(a + 3, gv.w);
    }
    __syncthreads();
    int i0 = b << SH;
    for (int k = tid; k < NPB; k += 256) {
        int i = i0 + k;
        if (i >= NN) continue;
        float dv = dis[i];
        float4 gs = gin[i];
        float h0 = tanhf(dv * (acc[k * 4 + 0] + gs.x) + bias[0]);
        float h1 = tanhf(dv * (acc[k * 4 + 1] + gs.y) + bias[1]);
        float h2 = tanhf(dv * (acc[k * 4 + 2] + gs.z) + bias[2]);
        float h3 = tanhf(dv * (acc[k * 4 + 3] + gs.w) + bias[3]);
        float2 o;
        o.x = dv * (h0 * W[0] + h1 * W[2] + h2 * W[4] + h3 * W[6]);
        o.y = dv * (h0 * W[1] + h1 * W[3] + h2 * W[5] + h3 * W[7]);
        gout[i] = o;
    }
}

// final layer: gin f2 -> h=tanh(...), out = h@Wc + bc ; writes out f4 + hout f2
__global__ __launch_bounds__(256) void k_agg2out(const int* __restrict__ bbase,
                                                 const int* __restrict__ packed,
                                                 const float2* __restrict__ gin,
                                                 const float* __restrict__ dis,
                                                 const float* __restrict__ b3,
                                                 const float* __restrict__ Wc,
                                                 const float* __restrict__ bc,
                                                 float4* __restrict__ out,
                                                 float2* __restrict__ hout) {
    __shared__ float acc[NPB * 2];
    int tid = threadIdx.x, b = blockIdx.x;
    for (int k = tid; k < NPB * 2; k += 256) acc[k] = 0.f;
    __syncthreads();
    int e0 = bbase[b], e1 = bbase[b + 1];
    for (int e = e0 + tid; e < e1; e += 256) {
        int p = packed[e];
        float2 gv = gin[p >> SH];
        float* a = &acc[(p & (NPB - 1)) * 2];
        unsafeAtomicAdd(a + 0, gv.x);
        unsafeAtomicAdd(a + 1, gv.y);
    }
    __syncthreads();
    int i0 = b << SH;
    for (int k = tid; k < NPB; k += 256) {
        int i = i0 + k;
        if (i >= NN) continue;
        float dv = dis[i];
        float2 gs = gin[i];
        float h0 = tanhf(dv * (acc[k * 2 + 0] + gs.x) + b3[0]);
        float h1 = tanhf(dv * (acc[k * 2 + 1] + gs.y) + b3[1]);
        float4 o;
        o.x = h0 * Wc[0] + h1 * Wc[4] + bc[0];
        o.y = h0 * Wc[1] + h1 * Wc[5] + bc[1];
        o.z = h0 * Wc[2] + h1 * Wc[6] + bc[2];
        o.w = h0 * Wc[3] + h1 * Wc[7] + bc[3];
        out[i] = o;
        hout[i] = make_float2(h0, h1);
    }
}

extern "C" void kernel_launch(void* const* d_in, const int* in_sizes, int n_in,
                              void* d_out, int out_size, void* d_ws, size_t ws_size,
                              hipStream_t stream) {
    const float* x  = (const float*)d_in[0];
    const int*   ei = (const int*)d_in[1];
    const float* W1 = (const float*)d_in[2];
    const float* b1 = (const float*)d_in[3];
    const float* W2 = (const float*)d_in[4];
    const float* b2 = (const float*)d_in[5];
    const float* W3 = (const float*)d_in[6];
    const float* b3 = (const float*)d_in[7];
    const float* Wc = (const float*)d_in[8];
    const float* bc = (const float*)d_in[9];

    const int n  = NN;
    const int ne = in_sizes[1] / 2;
    const int* src  = ei;
    const int* dstp = ei + ne;

    // workspace layout (bytes):
    // packed[ne] | dis[n] | g1[4n] | g2[4n] | g3[2n] | bcount | bbase[NBUCK+1] | cur
    char* base = (char*)d_ws;
    int*   packed = (int*)base;                       base += (size_t)ne * 4;
    float* dis    = (float*)base;                     base += (size_t)n * 4;
    float* g1     = (float*)base;                     base += (size_t)n * 16;
    float* g2     = (float*)base;                     base += (size_t)n * 16;
    float* g3     = (float*)base;                     base += (size_t)n * 8;
    int*   bcount = (int*)base;                       base += (NBUCK + 1) * 4;
    int*   bbase  = (int*)base;                       base += (NBUCK + 1) * 4;
    int*   cur    = (int*)base;

    float4* out4  = (float4*)d_out;
    float2* hout2 = (float2*)((float*)d_out + 4 * (size_t)n);

    hipMemsetAsync(bcount, 0, (NBUCK + 1) * 4, stream);
    k_bhist<<<512, 256, 0, stream>>>(dstp, bcount, ne);
    k_bscan<<<1, 1024, 0, stream>>>(bcount, bbase, cur);
    k_part<<<(ne + PT_TILE - 1) / PT_TILE, 256, 0, stream>>>(src, dstp, cur, packed, ne);
    k_deg<<<NBUCK, 256, 0, stream>>>(bbase, packed, dis);
    k_xw<<<(n + 3) / 4, 256, 0, stream>>>(x, W1, dis, (float4*)g1, n);
    k_agg44<<<NBUCK, 256, 0, stream>>>(bbase, packed, (const float4*)g1, dis, b1, W2,
                                       (float4*)g2);
    k_agg42<<<NBUCK, 256, 0, stream>>>(bbase, packed, (const float4*)g2, dis, b2, W3,
                                       (float2*)g3);
    k_agg2out<<<NBUCK, 256, 0, stream>>>(bbase, packed, (const float2*)g3, dis, b3, Wc, bc,
                                         out4, hout2);
}